// Round 9
// baseline (394.388 us; speedup 1.0000x reference)
//
#include <hip/hip_runtime.h>
#include <cstdint>
#include <cstddef>

#define NFEAT 512
#define NH1   256
#define NH2   128

#define SCAN_BLOCK 256
#define SCAN_ELEMS 4
#define SCAN_TILE  (SCAN_BLOCK * SCAN_ELEMS)   // 1024

#define P_CHUNKS 128          // edge chunks for privatized counting sort
#define NWMAX    25088        // LDS packed words (2 nodes/word), >= ceil(N/2)

typedef __attribute__((ext_vector_type(8))) short short8;
typedef __attribute__((ext_vector_type(8))) unsigned short ushortx8;
typedef __attribute__((ext_vector_type(4))) float float4v;

__device__ __forceinline__ unsigned short f2bf(float f) {
    unsigned int u = __float_as_uint(f);
    u += 0x7fffu + ((u >> 16) & 1u);   // round-to-nearest-even
    return (unsigned short)(u >> 16);
}
__device__ __forceinline__ float bf2f(unsigned short u) {
    return __uint_as_float(((unsigned int)u) << 16);
}

__device__ __forceinline__ void load_lds16(const void* g, void* l) {
    __builtin_amdgcn_global_load_lds(
        (const __attribute__((address_space(1))) void*)g,
        (__attribute__((address_space(3))) void*)l, 16, 0, 0);
}

// ================= CSR build: packed-u16 counting sort =================
// Counts fit u16: per-chunk count <= CE=6250 < 2^16; node degree is
// Poisson(E/N = 16) so deg << 2^16 (packed column sums never carry).

// Phase A: single pass per chunk; 2-nodes-per-word packed LDS histogram.
__global__ __launch_bounds__(256) void k_hist(const int* __restrict__ dst,
                                              unsigned int* __restrict__ hist,
                                              int E, int CE, int NW) {
    __shared__ unsigned int lh[NWMAX];
    for (int i = threadIdx.x; i < NW; i += 256) lh[i] = 0;
    __syncthreads();
    const int c  = blockIdx.x;
    const int lo = c * CE;
    const int hi = lo + CE < E ? lo + CE : E;
    for (int e = lo + (int)threadIdx.x; e < hi; e += 256) {
        const int d = dst[e];
        atomicAdd(&lh[d >> 1], (d & 1) ? (1u << 16) : 1u);
    }
    __syncthreads();
    unsigned int* outp = hist + (size_t)c * NW;
    for (int i = threadIdx.x; i < NW; i += 256) outp[i] = lh[i];
}

// Phase B: packed column sums -> degi + dinv (one thread per word = 2 nodes).
__global__ void k_colreduce(const unsigned int* __restrict__ hist,
                            int* __restrict__ degi, float* __restrict__ dinv,
                            int NW, int N) {
    const int w = blockIdx.x * blockDim.x + threadIdx.x;
    if (w >= NW) return;
    unsigned int s = 0;
#pragma unroll 8
    for (int c = 0; c < P_CHUNKS; ++c) s += hist[(size_t)c * NW + w];
    const int d0 = s & 0xffff, d1 = s >> 16;
    const int n0 = 2 * w, n1 = 2 * w + 1;
    if (n0 < N) { degi[n0] = d0; dinv[n0] = rsqrtf((float)(d0 + 1)); }
    if (n1 < N) { degi[n1] = d1; dinv[n1] = rsqrtf((float)(d1 + 1)); }
}

// Phase D: in-place packed exclusive prefix over chunks (node-local offsets).
__global__ void k_coloffs(unsigned int* __restrict__ hist, int NW) {
    const int w = blockIdx.x * blockDim.x + threadIdx.x;
    if (w >= NW) return;
    unsigned int run0 = 0, run1 = 0;
    for (int c = 0; c < P_CHUNKS; ++c) {
        unsigned int* p = &hist[(size_t)c * NW + w];
        const unsigned int t = *p;
        *p = run0 | (run1 << 16);
        run0 += t & 0xffff;
        run1 += t >> 16;
    }
}

// Phase E: place. Packed LDS cursor; returned old value = local slot.
__global__ __launch_bounds__(256) void k_place(const int* __restrict__ src,
                                               const int* __restrict__ dst,
                                               const unsigned int* __restrict__ hist,
                                               const int* __restrict__ row_start,
                                               int* __restrict__ csr_src,
                                               int E, int CE, int NW) {
    __shared__ unsigned int lcur[NWMAX];
    for (int i = threadIdx.x; i < NW; i += 256) lcur[i] = 0;
    __syncthreads();
    const int c  = blockIdx.x;
    const int lo = c * CE;
    const int hi = lo + CE < E ? lo + CE : E;
    const unsigned int* relrow = hist + (size_t)c * NW;
    for (int e = lo + (int)threadIdx.x; e < hi; e += 256) {
        const int d  = dst[e];
        const int w  = d >> 1;
        const int sh = (d & 1) * 16;
        const unsigned int old = atomicAdd(&lcur[w], 1u << sh);
        const int local = (old >> sh) & 0xffff;
        const int rel   = (relrow[w] >> sh) & 0xffff;   // L2-resident (100 KB row)
        const int pos   = row_start[d] + rel + local;   // L2-resident (200 KB)
        csr_src[pos] = src[e];
    }
}

// ---- three-phase exclusive scan over degi[0..N) -> row_start ----
__global__ __launch_bounds__(SCAN_BLOCK) void k_scan1(
    const int* __restrict__ degi, int* __restrict__ blocksums, int N) {
    __shared__ int red[SCAN_BLOCK];
    const int t = threadIdx.x;
    const int base = blockIdx.x * SCAN_TILE + t * SCAN_ELEMS;
    int s = 0;
#pragma unroll
    for (int i = 0; i < SCAN_ELEMS; ++i) {
        const int idx = base + i;
        if (idx < N) s += degi[idx];
    }
    red[t] = s;
    __syncthreads();
    for (int off = SCAN_BLOCK / 2; off > 0; off >>= 1) {
        if (t < off) red[t] += red[t + off];
        __syncthreads();
    }
    if (t == 0) blocksums[blockIdx.x] = red[0];
}

__global__ __launch_bounds__(1024) void k_scan2(
    const int* __restrict__ blocksums, int* __restrict__ blockoffs,
    int* __restrict__ row_start, int nb, int N) {
    __shared__ int sm[1024];
    const int t = threadIdx.x;
    const int v = (t < nb) ? blocksums[t] : 0;
    sm[t] = v;
    __syncthreads();
    for (int off = 1; off < 1024; off <<= 1) {
        const int x = (t >= off) ? sm[t - off] : 0;
        __syncthreads();
        sm[t] += x;
        __syncthreads();
    }
    if (t < nb) blockoffs[t] = sm[t] - v;
    if (t == 1023) row_start[N] = sm[1023];
}

__global__ __launch_bounds__(SCAN_BLOCK) void k_scan3(
    const int* __restrict__ degi, const int* __restrict__ blockoffs,
    int* __restrict__ row_start, int N) {
    __shared__ int tsum[SCAN_BLOCK];
    const int t = threadIdx.x;
    const int base = blockIdx.x * SCAN_TILE + t * SCAN_ELEMS;
    int v[SCAN_ELEMS];
    int s = 0;
#pragma unroll
    for (int i = 0; i < SCAN_ELEMS; ++i) {
        const int idx = base + i;
        v[i] = (idx < N) ? degi[idx] : 0;
        s += v[i];
    }
    tsum[t] = s;
    __syncthreads();
    for (int off = 1; off < SCAN_BLOCK; off <<= 1) {
        const int x = (t >= off) ? tsum[t - off] : 0;
        __syncthreads();
        tsum[t] += x;
        __syncthreads();
    }
    int excl = blockoffs[blockIdx.x] + tsum[t] - s;
#pragma unroll
    for (int i = 0; i < SCAN_ELEMS; ++i) {
        const int idx = base + i;
        if (idx < N) row_start[idx] = excl;
        excl += v[i];
    }
}

// ---------------- conversions ----------------
__global__ void k_cvt_x(const float* __restrict__ x, const float* __restrict__ dinv,
                        unsigned short* __restrict__ xb, int Nrows, int Mp) {
    int i = blockIdx.x * blockDim.x + threadIdx.x;   // one thread per 4 elements
    int total = Mp * (NFEAT / 4);
    if (i >= total) return;
    int row = i / (NFEAT / 4);
    int q   = (i % (NFEAT / 4)) * 4;
    ushort4 o;
    if (row < Nrows) {
        const float w = dinv[row];
        const float4 v = *(const float4*)&x[(size_t)row * NFEAT + q];
        o.x = f2bf(v.x * w); o.y = f2bf(v.y * w);
        o.z = f2bf(v.z * w); o.w = f2bf(v.w * w);
    } else {
        o.x = 0; o.y = 0; o.z = 0; o.w = 0;
    }
    *(ushort4*)&xb[(size_t)row * NFEAT + q] = o;
}

__global__ void k_cvt_wt(const float* __restrict__ W, unsigned short* __restrict__ Wt,
                         int K, int Nc) {
    int i = blockIdx.x * blockDim.x + threadIdx.x;
    if (i >= K * Nc) return;
    int k = i / Nc, n = i % Nc;
    Wt[(size_t)n * K + k] = f2bf(W[(size_t)k * Nc + n]);
}

// ---------------- bf16 MFMA GEMM ----------------
__global__ __launch_bounds__(256) void gemm_bf16(
    const unsigned short* __restrict__ A, const unsigned short* __restrict__ Bt,
    unsigned short* __restrict__ C, int N, int K) {
    __shared__ unsigned short As[128 * 32];
    __shared__ unsigned short Bs[128 * 32];
    const int t    = threadIdx.x;
    const int wave = t >> 6, lane = t & 63;
    const int row0 = blockIdx.y * 128, col0 = blockIdx.x * 128;
    const int wm = (wave >> 1) * 64, wn = (wave & 1) * 64;
    const int sr = lane >> 2;
    const int sk = (lane & 3) * 8;
    const int quad = lane >> 4, l15 = lane & 15;

    const int ca = wave * 2;
    const unsigned short* gA0 = A  + (size_t)(row0 + ca * 16 + sr) * K + sk;
    const unsigned short* gA1 = gA0 + (size_t)16 * K;
    const unsigned short* gB0 = Bt + (size_t)(col0 + ca * 16 + sr) * K + sk;
    const unsigned short* gB1 = gB0 + (size_t)16 * K;
    unsigned short* lA0 = &As[ca * 512];
    unsigned short* lA1 = &As[(ca + 1) * 512];
    unsigned short* lB0 = &Bs[ca * 512];
    unsigned short* lB1 = &Bs[(ca + 1) * 512];

    float4v acc[4][4] = {};

    for (int k0 = 0; k0 < K; k0 += 32) {
        __syncthreads();
        load_lds16(gA0 + k0, lA0);
        load_lds16(gA1 + k0, lA1);
        load_lds16(gB0 + k0, lB0);
        load_lds16(gB1 + k0, lB1);
        __syncthreads();

        short8 a[4], b[4];
#pragma unroll
        for (int i = 0; i < 4; ++i) {
            a[i] = *(const short8*)&As[(wm + i * 16 + l15) * 32 + quad * 8];
            b[i] = *(const short8*)&Bs[(wn + i * 16 + l15) * 32 + quad * 8];
        }
#pragma unroll
        for (int mt = 0; mt < 4; ++mt)
#pragma unroll
            for (int nt = 0; nt < 4; ++nt)
                acc[mt][nt] = __builtin_amdgcn_mfma_f32_16x16x32_bf16(
                    a[mt], b[nt], acc[mt][nt], 0, 0, 0);
    }

    // C/D layout: col = lane&15, row = (lane>>4)*4 + reg   [m89-verified]
#pragma unroll
    for (int mt = 0; mt < 4; ++mt) {
#pragma unroll
        for (int nt = 0; nt < 4; ++nt) {
            const int c = col0 + wn + nt * 16 + l15;
#pragma unroll
            for (int r = 0; r < 4; ++r) {
                const int row = row0 + wm + mt * 16 + quad * 4 + r;
                C[(size_t)row * N + c] = f2bf(acc[mt][nt][r]);
            }
        }
    }
}

// ---------------- CSR gather aggregation (16B lanes, multi-edge waves) ----
// h rows pre-scaled by dinv[src]. Lane covers 8 features (16 B); a wave-load
// covers EPW = 64/(F/8) edge rows at once. Cross-slot shfl_xor reduction.
template <int F, bool RELU, bool OUTF32>
__global__ __launch_bounds__(256) void k_gather(
    const int* __restrict__ row_start, const int* __restrict__ csr_src,
    const float* __restrict__ dinv, const unsigned short* __restrict__ h,
    const float* __restrict__ bias, unsigned short* __restrict__ ob,
    float* __restrict__ of, int N) {
    constexpr int LPE = F / 8;      // lanes per edge row: 32 (F=256) / 16 (F=128)
    constexpr int EPW = 64 / LPE;   // edge rows per wave-load: 2 / 4
    const int gid  = blockIdx.x * blockDim.x + threadIdx.x;
    const int node = gid >> 6;
    const int lane = gid & 63;
    if (node >= N) return;
    const int slot = lane / LPE;
    const int fb   = (lane % LPE) * 8;
    const float wd = dinv[node];
    const int jb = row_start[node];
    const int je = row_start[node + 1];
    const unsigned short* hf = h + fb;

    float acc[8];
    if (slot == 0) {   // self-loop term, counted once (slot 0 only)
        const ushortx8 v = *(const ushortx8*)(hf + (size_t)node * F);
#pragma unroll
        for (int e = 0; e < 8; ++e) acc[e] = bf2f(v[e]);
    } else {
#pragma unroll
        for (int e = 0; e < 8; ++e) acc[e] = 0.f;
    }

    for (int j0 = jb; j0 < je; j0 += 64) {
        int jj = j0 + lane;
        if (jj >= je) jj = je - 1;
        const int myi = csr_src[jj];
        const int rem = je - j0;
        const int cnt = rem < 64 ? rem : 64;
        int i = 0;
        for (; i + 4 * EPW <= cnt; i += 4 * EPW) {   // 4 x 16B loads in flight
            const int s0 = __shfl(myi, i + 0 * EPW + slot);
            const int s1 = __shfl(myi, i + 1 * EPW + slot);
            const int s2 = __shfl(myi, i + 2 * EPW + slot);
            const int s3 = __shfl(myi, i + 3 * EPW + slot);
            const ushortx8 v0 = *(const ushortx8*)(hf + (size_t)s0 * F);
            const ushortx8 v1 = *(const ushortx8*)(hf + (size_t)s1 * F);
            const ushortx8 v2 = *(const ushortx8*)(hf + (size_t)s2 * F);
            const ushortx8 v3 = *(const ushortx8*)(hf + (size_t)s3 * F);
#pragma unroll
            for (int e = 0; e < 8; ++e)
                acc[e] += (bf2f(v0[e]) + bf2f(v1[e])) + (bf2f(v2[e]) + bf2f(v3[e]));
        }
        for (; i < cnt; i += EPW) {
            const int idx = i + slot;
            const bool ok = idx < cnt;
            const int s = __shfl(myi, ok ? idx : cnt - 1);
            const ushortx8 v = *(const ushortx8*)(hf + (size_t)s * F);
            if (ok) {
#pragma unroll
                for (int e = 0; e < 8; ++e) acc[e] += bf2f(v[e]);
            }
        }
    }

#pragma unroll
    for (int e = 0; e < 8; ++e) {   // reduce across slots
        if (EPW == 4) acc[e] += __shfl_xor(acc[e], 16);
        acc[e] += __shfl_xor(acc[e], 32);
    }

    if (slot == 0) {
        const float4 b0 = *(const float4*)&bias[fb];
        const float4 b1 = *(const float4*)&bias[fb + 4];
        float r[8];
        r[0] = fmaf(acc[0], wd, b0.x); r[1] = fmaf(acc[1], wd, b0.y);
        r[2] = fmaf(acc[2], wd, b0.z); r[3] = fmaf(acc[3], wd, b0.w);
        r[4] = fmaf(acc[4], wd, b1.x); r[5] = fmaf(acc[5], wd, b1.y);
        r[6] = fmaf(acc[6], wd, b1.z); r[7] = fmaf(acc[7], wd, b1.w);
        if (OUTF32) {
            float* op = &of[(size_t)node * F + fb];
            *(float4*)op       = make_float4(r[0], r[1], r[2], r[3]);
            *(float4*)(op + 4) = make_float4(r[4], r[5], r[6], r[7]);
        } else {
            ushortx8 o;
#pragma unroll
            for (int e = 0; e < 8; ++e) {
                float v = r[e];
                if (RELU) v = fmaxf(v, 0.f);
                o[e] = f2bf(v * wd);   // pre-scale for next layer
            }
            *(ushortx8*)&ob[(size_t)node * F + fb] = o;
        }
    }
}

extern "C" void kernel_launch(void* const* d_in, const int* in_sizes, int n_in,
                              void* d_out, int out_size, void* d_ws, size_t ws_size,
                              hipStream_t stream) {
    const float* x   = (const float*)d_in[0];
    const int*   ei  = (const int*)d_in[1];
    const float* W1  = (const float*)d_in[2];
    const float* b1  = (const float*)d_in[3];
    const float* W2  = (const float*)d_in[4];
    const float* b2  = (const float*)d_in[5];
    float*       out = (float*)d_out;

    const int N = in_sizes[0] / NFEAT;           // 50000
    const int E = in_sizes[1] / 2;               // 800000
    const int Mp = ((N + 127) / 128) * 128;      // 50048
    const int* srcp = ei;
    const int* dstp = ei + E;
    const int nScanBlocks = (N + SCAN_TILE - 1) / SCAN_TILE;   // 49
    const int CE = (E + P_CHUNKS - 1) / P_CHUNKS;              // 6250
    const int NW = (N + 1) / 2;                                // 25000 packed words

    // workspace layout (256B aligned chunks)
    char* wsb = (char*)d_ws;
    auto take = [&](size_t bytes) {
        char* p = wsb;
        wsb += (bytes + 255) & ~(size_t)255;
        return p;
    };
    int*   degi      = (int*)take((size_t)N * 4);
    int*   row_start = (int*)take((size_t)(N + 1) * 4);
    int*   csr_src   = (int*)take((size_t)E * 4);
    int*   blocksums = (int*)take((size_t)1024 * 4);
    int*   blockoffs = (int*)take((size_t)1024 * 4);
    float* dinv      = (float*)take((size_t)N * 4);
    unsigned short* xb  = (unsigned short*)take((size_t)Mp * NFEAT * 2);  // also h2
    unsigned short* W1t = (unsigned short*)take((size_t)NH1 * NFEAT * 2);
    unsigned short* W2t = (unsigned short*)take((size_t)NH2 * NH1 * 2);
    // union region: hist (12.8 MB, dead before GEMM1) overlaps h + h1 (51.2 MB)
    const size_t hBytes    = (size_t)Mp * NH1 * 2;
    const size_t histBytes = (size_t)P_CHUNKS * NW * 4;
    char* big = take(histBytes > 2 * hBytes ? histBytes : 2 * hBytes);
    unsigned int*   hist = (unsigned int*)big;
    unsigned short* h    = (unsigned short*)big;
    unsigned short* h1   = (unsigned short*)(big + hBytes);
    unsigned short* h2   = xb;                   // xb dead after GEMM1

    // ---- CSR build (packed u16 counting sort) + dinv ----
    k_hist<<<P_CHUNKS, 256, 0, stream>>>(dstp, hist, E, CE, NW);
    k_colreduce<<<(NW + 255) / 256, 256, 0, stream>>>(hist, degi, dinv, NW, N);
    k_scan1<<<nScanBlocks, SCAN_BLOCK, 0, stream>>>(degi, blocksums, N);
    k_scan2<<<1, 1024, 0, stream>>>(blocksums, blockoffs, row_start, nScanBlocks, N);
    k_scan3<<<nScanBlocks, SCAN_BLOCK, 0, stream>>>(degi, blockoffs, row_start, N);
    k_coloffs<<<(NW + 255) / 256, 256, 0, stream>>>(hist, NW);
    k_place<<<P_CHUNKS, 256, 0, stream>>>(srcp, dstp, hist, row_start, csr_src, E, CE, NW);

    // ---- conversions ----
    {
        int total = Mp * (NFEAT / 4);
        k_cvt_x<<<(total + 255) / 256, 256, 0, stream>>>(x, dinv, xb, N, Mp);
    }
    k_cvt_wt<<<(NFEAT * NH1 + 255) / 256, 256, 0, stream>>>(W1, W1t, NFEAT, NH1);
    k_cvt_wt<<<(NH1 * NH2 + 255) / 256, 256, 0, stream>>>(W2, W2t, NH1, NH2);

    // ---- layer 1: h = (x*dinv)@W1 (bf16) ; h1 = relu(...)*dinv (bf16) ----
    {
        dim3 g(NH1 / 128, Mp / 128);
        gemm_bf16<<<g, 256, 0, stream>>>(xb, W1t, h, NH1, NFEAT);
    }
    {
        int total = N * 64;
        k_gather<NH1, true, false><<<(total + 255) / 256, 256, 0, stream>>>(
            row_start, csr_src, dinv, h, b1, h1, nullptr, N);
    }

    // ---- layer 2: h2 = h1s@W2 (bf16) ; out = gather + b2 (fp32) ----
    {
        dim3 g(NH2 / 128, Mp / 128);
        gemm_bf16<<<g, 256, 0, stream>>>(h1, W2t, h2, NH2, NH1);
    }
    {
        int total = N * 64;
        k_gather<NH2, false, true><<<(total + 255) / 256, 256, 0, stream>>>(
            row_start, csr_src, dinv, h2, b2, nullptr, out, N);
    }
}